// Round 16
// baseline (97.140 us; speedup 1.0000x reference)
//
#include <hip/hip_runtime.h>
#include <stdint.h>
#include <math.h>

#pragma clang fp contract(off)

#define N_ROWS 1048576
#define N_CLS  20
#define K_TOP  2000
#define CAND_MAX 8192
#define KEYS_MAX 8184
#define NBINS  4096
#define H_COPIES 4
#define DELTA_ULP 4096u

// scal slots (dwords) -- inside the zeroed region
#define SC_CNT   0
#define SC_MAXK  1
#define SC_DONE  2   // maskscan done-counter
#define SC_BAR   3   // select barrier-1 arrival counter
#define SC_FLAG  4   // select barrier-1 release = Tk+1 (nonzero)
#define SC_BAR2  5   // select barrier-2 arrival counter
#define SC_FLAG2 6   // select barrier-2 release = M+1  (nonzero)

// ws layout
static constexpr size_t OFF_MKEY = 0;                              // u32[N]          4 MB
static constexpr size_t OFF_CLS  = OFF_MKEY + 4ull * N_ROWS;       // u8[N]           1 MB
static constexpr size_t OFF_HIST = OFF_CLS + (size_t)N_ROWS;       // u32[4*4096] -- zero region start
static constexpr size_t OFF_SCAL = OFF_HIST + 4ull * H_COPIES * NBINS;  // u32[16]
static constexpr size_t OFF_GRP  = OFF_SCAL + 64;                  // u64[32]     -- zero region end (16464 dw)
static constexpr size_t OFF_CAND = OFF_GRP + 256;                  // u64[CAND_MAX]
static constexpr size_t OFF_MASK = OFF_CAND + 8ull * CAND_MAX;     // u64[K_TOP*32]

__device__ __forceinline__ uint32_t mono_key(float f) {
    uint32_t u = __float_as_uint(f);
    return u ^ ((u & 0x80000000u) ? 0xFFFFFFFFu : 0x80000000u);
}
__device__ __forceinline__ float mono_inv(uint32_t k) {
    uint32_t u = (k & 0x80000000u) ? (k ^ 0x80000000u) : ~k;
    return __uint_as_float(u);
}

// ---- D1: PURE read+argmax+write (proven sub-fill R14/R15). Blocks 0..7 zero
//      hist/scal/grp with plain stores (no consumer in-kernel; boundary orders them).
__global__ __launch_bounds__(256) void k_scoremax(const float* __restrict__ logits,
                                                  uint32_t* __restrict__ mkey,
                                                  uint8_t* __restrict__ cls,
                                                  uint32_t* __restrict__ zreg) {
    int t = threadIdx.x, b = blockIdx.x;
    if (b < 8) {
#pragma unroll
        for (int k = 0; k < 8; ++k) zreg[b * 256 + t + k * 2048] = 0;   // 16384 dwords
        if (b == 7 && t < 80) zreg[16384 + t] = 0;                      // scal + grp
    }
    size_t r0 = (size_t)b * 1024 + t;              // rows r0, +256, +512, +768
    const float4* p0 = (const float4*)(logits + r0 * N_CLS);
    const float4* p1 = (const float4*)(logits + (r0 + 256) * N_CLS);
    const float4* p2 = (const float4*)(logits + (r0 + 512) * N_CLS);
    const float4* p3 = (const float4*)(logits + (r0 + 768) * N_CLS);
    float4 a0 = p0[0], a1 = p0[1], a2 = p0[2], a3 = p0[3], a4 = p0[4];
    float4 b0 = p1[0], b1 = p1[1], b2 = p1[2], b3 = p1[3], b4 = p1[4];
    float4 c0 = p2[0], c1 = p2[1], c2 = p2[2], c3 = p2[3], c4 = p2[4];
    float4 d0 = p3[0], d1 = p3[1], d2 = p3[2], d3 = p3[3], d4 = p3[4];
    __builtin_amdgcn_sched_barrier(0);             // all 20 loads precede all uses

#define CK(mm, cc, val, idx) if ((val) > mm) { mm = (val); cc = (idx); }
    float mA = a0.x; int cA = 0;
    CK(mA, cA, a0.y, 1)  CK(mA, cA, a0.z, 2)  CK(mA, cA, a0.w, 3)
    CK(mA, cA, a1.x, 4)  CK(mA, cA, a1.y, 5)  CK(mA, cA, a1.z, 6)  CK(mA, cA, a1.w, 7)
    CK(mA, cA, a2.x, 8)  CK(mA, cA, a2.y, 9)  CK(mA, cA, a2.z, 10) CK(mA, cA, a2.w, 11)
    CK(mA, cA, a3.x, 12) CK(mA, cA, a3.y, 13) CK(mA, cA, a3.z, 14) CK(mA, cA, a3.w, 15)
    CK(mA, cA, a4.x, 16) CK(mA, cA, a4.y, 17) CK(mA, cA, a4.z, 18) CK(mA, cA, a4.w, 19)
    float mB = b0.x; int cB = 0;
    CK(mB, cB, b0.y, 1)  CK(mB, cB, b0.z, 2)  CK(mB, cB, b0.w, 3)
    CK(mB, cB, b1.x, 4)  CK(mB, cB, b1.y, 5)  CK(mB, cB, b1.z, 6)  CK(mB, cB, b1.w, 7)
    CK(mB, cB, b2.x, 8)  CK(mB, cB, b2.y, 9)  CK(mB, cB, b2.z, 10) CK(mB, cB, b2.w, 11)
    CK(mB, cB, b3.x, 12) CK(mB, cB, b3.y, 13) CK(mB, cB, b3.z, 14) CK(mB, cB, b3.w, 15)
    CK(mB, cB, b4.x, 16) CK(mB, cB, b4.y, 17) CK(mB, cB, b4.z, 18) CK(mB, cB, b4.w, 19)
    float mC = c0.x; int cC = 0;
    CK(mC, cC, c0.y, 1)  CK(mC, cC, c0.z, 2)  CK(mC, cC, c0.w, 3)
    CK(mC, cC, c1.x, 4)  CK(mC, cC, c1.y, 5)  CK(mC, cC, c1.z, 6)  CK(mC, cC, c1.w, 7)
    CK(mC, cC, c2.x, 8)  CK(mC, cC, c2.y, 9)  CK(mC, cC, c2.z, 10) CK(mC, cC, c2.w, 11)
    CK(mC, cC, c3.x, 12) CK(mC, cC, c3.y, 13) CK(mC, cC, c3.z, 14) CK(mC, cC, c3.w, 15)
    CK(mC, cC, c4.x, 16) CK(mC, cC, c4.y, 17) CK(mC, cC, c4.z, 18) CK(mC, cC, c4.w, 19)
    float mD = d0.x; int cD = 0;
    CK(mD, cD, d0.y, 1)  CK(mD, cD, d0.z, 2)  CK(mD, cD, d0.w, 3)
    CK(mD, cD, d1.x, 4)  CK(mD, cD, d1.y, 5)  CK(mD, cD, d1.z, 6)  CK(mD, cD, d1.w, 7)
    CK(mD, cD, d2.x, 8)  CK(mD, cD, d2.y, 9)  CK(mD, cD, d2.z, 10) CK(mD, cD, d2.w, 11)
    CK(mD, cD, d3.x, 12) CK(mD, cD, d3.y, 13) CK(mD, cD, d3.z, 14) CK(mD, cD, d3.w, 15)
    CK(mD, cD, d4.x, 16) CK(mD, cD, d4.y, 17) CK(mD, cD, d4.z, 18) CK(mD, cD, d4.w, 19)
#undef CK

    mkey[r0]       = mono_key(mA);  cls[r0]       = (uint8_t)cA;
    mkey[r0 + 256] = mono_key(mB);  cls[r0 + 256] = (uint8_t)cB;
    mkey[r0 + 512] = mono_key(mC);  cls[r0 + 512] = (uint8_t)cC;
    mkey[r0 + 768] = mono_key(mD);  cls[r0 + 768] = (uint8_t)cD;
}

// ---- D2: hist + find + compact + RANK in ONE kernel (R15's proven single-word
//      barrier, used twice). 256 blocks (1/CU, co-resident). LDS is a manual union:
//      phases 1-2 use hh[4096](16K)+stg[1024](8K); phase 3 reuses the same 64KB as
//      keys[8184]; scalars live in the last 64B. cand handoff is atomicExch-write /
//      atomicOr-fetch (device-coherent across XCDs, R5-proven).
__global__ __launch_bounds__(256) void k_select(const uint32_t* __restrict__ mkey,
                                                uint32_t* __restrict__ hist,
                                                uint32_t* __restrict__ scal,
                                                unsigned long long* __restrict__ cand,
                                                const float* __restrict__ deltas,
                                                const float* __restrict__ locs,
                                                const int* __restrict__ stridep,
                                                const uint8_t* __restrict__ cls,
                                                float* __restrict__ out) {
    __shared__ __align__(16) unsigned char smem[65536];
    uint32_t* hh   = (uint32_t*)smem;                       // [0,16384)  phases 1-2
    uint64_t* stg  = (uint64_t*)(smem + 16384);             // [16384,24576) phase 2
    uint64_t* keys = (uint64_t*)smem;                       // [0,65472)  phase 3
    uint32_t* sv   = (uint32_t*)(smem + 65472);             // 0=bc 1=cnt 2=gbase 3=islast
    int t = threadIdx.x, b = blockIdx.x;
    int lane = t & 63;
    if (t == 0) sv[1] = 0;
    for (int i = t; i < NBINS; i += 256) hh[i] = 0;
    __syncthreads();

    // ---- phase 1: 16 keys/thread into registers -> LDS 12-bit hist
    const uint4* m4 = (const uint4*)mkey;
    size_t base = (size_t)b * 1024;                // uint4 index; 4096 rows/block
    uint4 v0 = m4[base + t], v1 = m4[base + 256 + t];
    uint4 v2 = m4[base + 512 + t], v3 = m4[base + 768 + t];
    atomicAdd(&hh[v0.x >> 20], 1u); atomicAdd(&hh[v0.y >> 20], 1u);
    atomicAdd(&hh[v0.z >> 20], 1u); atomicAdd(&hh[v0.w >> 20], 1u);
    atomicAdd(&hh[v1.x >> 20], 1u); atomicAdd(&hh[v1.y >> 20], 1u);
    atomicAdd(&hh[v1.z >> 20], 1u); atomicAdd(&hh[v1.w >> 20], 1u);
    atomicAdd(&hh[v2.x >> 20], 1u); atomicAdd(&hh[v2.y >> 20], 1u);
    atomicAdd(&hh[v2.z >> 20], 1u); atomicAdd(&hh[v2.w >> 20], 1u);
    atomicAdd(&hh[v3.x >> 20], 1u); atomicAdd(&hh[v3.y >> 20], 1u);
    atomicAdd(&hh[v3.z >> 20], 1u); atomicAdd(&hh[v3.w >> 20], 1u);
    __syncthreads();

    // publish nonzero bins (4 spread copies), drain, arrive (t==0 only)
    uint32_t cp = (uint32_t)((b & (H_COPIES - 1)) << 12);
    unsigned long long dummy = 0;
    for (int i = 0; i < 16; ++i) {
        uint32_t h = hh[t * 16 + i];
        if (h) dummy += atomicAdd(&hist[cp + t * 16 + i], h);
    }
    asm volatile("" :: "v"(dummy));
    asm volatile("s_waitcnt vmcnt(0) lgkmcnt(0)" ::: "memory");
    __syncthreads();
    if (t == 0) {
        uint32_t old = atomicAdd(&scal[SC_BAR], 1u);
        sv[3] = (old == 255u) ? 1u : 0u;
    }
    __syncthreads();

    if (sv[3]) {
        // find12 (last block): thread t sums bins [t*16,t*16+16) over 4 copies
        uint32_t bv[16]; uint32_t ct = 0;
#pragma unroll
        for (int i = 0; i < 16; ++i) {
            uint32_t s = 0;
#pragma unroll
            for (int k = 0; k < H_COPIES; ++k) s += atomicAdd(&hist[(k << 12) + t * 16 + i], 0u);
            bv[i] = s; ct += s;
        }
        hh[t] = ct;                                 // reuse hh[0..255] as suffix array
        __syncthreads();
        for (int off = 1; off < 256; off <<= 1) {
            uint32_t v = (t + off < 256) ? hh[t + off] : 0;
            __syncthreads();
            hh[t] += v;
            __syncthreads();
        }
        if (hh[t] >= (uint32_t)K_TOP && (t == 255 || hh[t + 1] < (uint32_t)K_TOP)) {
            uint32_t cum = (t == 255) ? 0u : hh[t + 1];
            int i = 15;
            for (; i >= 0; --i) { cum += bv[i]; if (cum >= (uint32_t)K_TOP) break; }
            if (i < 0) i = 0;
            uint32_t tk = ((uint32_t)(t * 16 + i)) << 20;
            // δ-ULP margin: covers rounded-sigmoid ties (~11 key-ULPs) with 370x slack.
            uint32_t Tk = (tk > DELTA_ULP) ? (tk - DELTA_ULP) : 0u;
            atomicExch(&scal[SC_FLAG], Tk + 1u);    // nonzero release word
        }
    }
    for (;;) {                                     // barrier-1 release poll (t==0 only)
        if (t == 0) sv[0] = atomicAdd(&scal[SC_FLAG], 0u);
        __syncthreads();
        if (sv[0] != 0u) break;
        __builtin_amdgcn_s_sleep(32);
    }
    uint32_t T = sv[0] - 1u;
    __syncthreads();

    // ---- phase 2: compact from registers (mkey >= T); sigmoid only for passing rows
#define CSLOT(u, roff) {                                                         \
        uint32_t uu = (u);                                                       \
        bool pass = uu >= T;                                                     \
        unsigned long long bal = __ballot(pass);                                 \
        if (bal) {                                                               \
            uint32_t wbase = 0;                                                  \
            if (lane == 0) wbase = atomicAdd(&sv[1], (uint32_t)__popcll(bal));   \
            wbase = __shfl(wbase, 0);                                            \
            if (pass) {                                                          \
                uint32_t pos = wbase + (uint32_t)__popcll(bal & ((1ull << lane) - 1ull)); \
                if (pos < 1024) {                                                \
                    float m = mono_inv(uu);                                      \
                    float ef = (float)exp(-(double)m);                           \
                    float s = 1.0f / (1.0f + ef);                                \
                    stg[pos] = ((uint64_t)(~__float_as_uint(s)) << 32) | (roff); \
                }                                                                \
            }                                                                    \
        }                                                                        \
    }
    uint32_t rb = (uint32_t)((base + t) * 4);
    CSLOT(v0.x, rb + 0) CSLOT(v0.y, rb + 1) CSLOT(v0.z, rb + 2) CSLOT(v0.w, rb + 3)
    rb = (uint32_t)((base + 256 + t) * 4);
    CSLOT(v1.x, rb + 0) CSLOT(v1.y, rb + 1) CSLOT(v1.z, rb + 2) CSLOT(v1.w, rb + 3)
    rb = (uint32_t)((base + 512 + t) * 4);
    CSLOT(v2.x, rb + 0) CSLOT(v2.y, rb + 1) CSLOT(v2.z, rb + 2) CSLOT(v2.w, rb + 3)
    rb = (uint32_t)((base + 768 + t) * 4);
    CSLOT(v3.x, rb + 0) CSLOT(v3.y, rb + 1) CSLOT(v3.z, rb + 2) CSLOT(v3.w, rb + 3)
#undef CSLOT
    __syncthreads();
    uint32_t n = sv[1]; if (n > 1024) n = 1024;
    if (t == 0 && n) sv[2] = atomicAdd(&scal[SC_CNT], n);
    __syncthreads();
    dummy = 0;
    if (n) {
        uint32_t gb = sv[2];
        for (uint32_t i = t; i < n; i += 256) {
            uint32_t pos = gb + i;
            if (pos < (uint32_t)CAND_MAX)
                dummy += atomicExch(&cand[pos], (unsigned long long)stg[i]);  // device-coherent
        }
    }
    asm volatile("" :: "v"(dummy));
    asm volatile("s_waitcnt vmcnt(0) lgkmcnt(0)" ::: "memory");
    __syncthreads();

    // ---- barrier 2: last block publishes M+1
    if (t == 0) {
        uint32_t old = atomicAdd(&scal[SC_BAR2], 1u);
        sv[3] = (old == 255u) ? 1u : 0u;
    }
    __syncthreads();
    if (sv[3] && t == 0) {
        uint32_t M = atomicAdd(&scal[SC_CNT], 0u);
        atomicExch(&scal[SC_FLAG2], M + 1u);        // M >= K_TOP > 0
    }
    for (;;) {
        if (t == 0) sv[0] = atomicAdd(&scal[SC_FLAG2], 0u);
        __syncthreads();
        if (sv[0] != 0u) break;
        __builtin_amdgcn_s_sleep(32);
    }
    uint32_t M = sv[0] - 1u;
    if (M > (uint32_t)KEYS_MAX) M = KEYS_MAX;
    __syncthreads();                                // stg/hh dead -> keys may overwrite

    // ---- phase 3: rank-by-counting (R11-proven, M-insensitive). keys via atomic fetch.
    for (uint32_t i = t; i < M; i += 256)
        keys[i] = (uint64_t)atomicOr(&cand[i], 0ull);
    __syncthreads();
    int wid = t >> 6;
    float stridef = (float)(*stridep);
    float wmx = -3.4e38f;
    for (uint32_t c = (uint32_t)b * 4 + wid; c < M; c += 1024) {
        uint64_t myk = keys[c];
        uint32_t r = 0;
        uint32_t j = lane;
        for (; j + 192 < M; j += 256) {             // 4 independent LDS reads -> pipelined
            uint64_t k0 = keys[j], k1 = keys[j + 64], k2 = keys[j + 128], k3 = keys[j + 192];
            r += (uint32_t)(k0 < myk) + (uint32_t)(k1 < myk)
               + (uint32_t)(k2 < myk) + (uint32_t)(k3 < myk);
        }
        for (; j < M; j += 64) r += (keys[j] < myk) ? 1u : 0u;
#pragma unroll
        for (int o = 32; o > 0; o >>= 1) r += __shfl_down(r, o);
        if (lane == 0 && r < (uint32_t)K_TOP) {
            uint32_t row = (uint32_t)myk & (N_ROWS - 1);
            float s = __uint_as_float(~(uint32_t)(myk >> 32));
            float4 dl = ((const float4*)deltas)[row];
            float2 lc = ((const float2*)locs)[row];
            float d0 = dl.x * stridef, d1 = dl.y * stridef, d2 = dl.z * stridef, d3 = dl.w * stridef;
            float b0f = lc.x - d0, b1f = lc.y - d1, b2f = lc.x + d2, b3f = lc.y + d3;
            float4 bx = { b0f, b1f, b2f, b3f };
            *(float4*)&out[4 * r] = bx;
            out[8000 + r] = s;
            out[10000 + r] = (float)cls[row];
            wmx = fmaxf(wmx, fmaxf(fmaxf(b0f, b1f), fmaxf(b2f, b3f)));
        }
    }
    if (lane == 0) atomicMax(&scal[SC_MAXK], mono_key(wmx));
}

// ---- D3: pairwise suppression mask (quirky IoU replicated exactly) + fused scan.
//      Skip-empty rows (grp-gated). Atomic-only handoff (proven R5/R7/R8).
__global__ __launch_bounds__(256) void k_maskscan(const float* __restrict__ out_ro,
                                                  uint32_t* __restrict__ scal,
                                                  uint64_t* __restrict__ mask,
                                                  unsigned long long* __restrict__ grp,
                                                  float* __restrict__ out) {
    __shared__ uint64_t wb[4][32];
    __shared__ int lastdone;
    int t = threadIdx.x;
    int lane = t & 63;
    int wid = t >> 6;
    int i = blockIdx.x * 4 + wid;                   // 2000 waves total
    float off1 = mono_inv(scal[SC_MAXK]) + 1.0f;    // max_coord + 1 (prev dispatch, coherent)
    float4 boxi = *(const float4*)&out_ro[4 * i];
    float oi = out_ro[10000 + i] * off1;
    float x1i = boxi.x + oi, y2i = boxi.y + oi, x2i = boxi.z + oi, y1i = boxi.w + oi;
    float ai = (x2i - x1i) * (y2i - y1i);
    uint64_t any = 0;
    for (int jb = 0; jb < 32; ++jb) {
        int j = jb * 64 + lane;
        bool sup = false;
        if (j < K_TOP && j > i) {
            float4 boxj = *(const float4*)&out_ro[4 * j];
            float oj = out_ro[10000 + j] * off1;
            float x1j = boxj.x + oj, y2j = boxj.y + oj, x2j = boxj.z + oj, y1j = boxj.w + oj;
            float aj = (x2j - x1j) * (y2j - y1j);
            float xx1 = fmaxf(x1i, x1j);
            float yy1 = fminf(y1i, y1j);
            float xx2 = fminf(x2i, x2j);
            float yy2 = fmaxf(y2i, y2j);
            float inter = fabsf(xx2 - xx1) * fabsf(yy2 - yy1);
            float iou = inter / ((ai + aj) - inter);
            sup = iou > 0.5f;
        }
        unsigned long long bits = __ballot(sup);
        if (lane == 0) wb[wid][jb] = bits;
        any |= bits;
    }
    unsigned long long dummy = 0;
    if (lane == 0 && any) {                         // rare: NMS barely suppresses here
        for (int jb = 0; jb < 32; ++jb)
            dummy += atomicExch(&mask[(size_t)i * 32 + jb], wb[wid][jb]);
        dummy += atomicOr(&grp[i >> 6], 1ull << (i & 63));
    }
    asm volatile("" :: "v"(dummy));                 // force atomic returns (vmcnt drained)
    asm volatile("s_waitcnt vmcnt(0) lgkmcnt(0)" ::: "memory");
    __syncthreads();
    if (t == 0) {
        unsigned old = atomicAdd(&scal[SC_DONE], 1u);
        lastdone = (old == (unsigned)(gridDim.x - 1)) ? 1 : 0;
    }
    __syncthreads();
    if (!lastdone) return;

    if (t < 64) {
        int l = t;                                  // lane w<32 holds active word w
        uint64_t g = (l < 32) ? atomicOr(&grp[l], 0ull) : 0ull;
        uint64_t active = ~0ull;
        if (__ballot(g != 0ull)) {
            for (int gg = 0; gg < 32; ++gg) {
                uint64_t nz = __shfl(g, gg);
                while (nz) {
                    int b = __ffsll((long long)nz) - 1;
                    nz &= nz - 1;
                    int ii = gg * 64 + b;
                    uint64_t aw = __shfl(active, gg);
                    bool kept = (aw >> b) & 1ull;
                    uint64_t m = (l < 32) ? atomicOr(&mask[(size_t)ii * 32 + l], 0ull) : 0ull;
                    if (kept) active &= ~m;
                }
            }
        }
        if (l < 32) {
            int limit = K_TOP - l * 64;
            int nvec = limit < 64 ? limit / 4 : 16;
            for (int v = 0; v < nvec; ++v) {
                float4 f;
                f.x = ((active >> (4 * v + 0)) & 1ull) ? 1.0f : 0.0f;
                f.y = ((active >> (4 * v + 1)) & 1ull) ? 1.0f : 0.0f;
                f.z = ((active >> (4 * v + 2)) & 1ull) ? 1.0f : 0.0f;
                f.w = ((active >> (4 * v + 3)) & 1ull) ? 1.0f : 0.0f;
                *(float4*)&out[12000 + l * 64 + 4 * v] = f;
            }
        }
    }
}

extern "C" void kernel_launch(void* const* d_in, const int* in_sizes, int n_in,
                              void* d_out, int out_size, void* d_ws, size_t ws_size,
                              hipStream_t stream) {
    const float* deltas = (const float*)d_in[0];
    const float* locs   = (const float*)d_in[1];
    const float* logits = (const float*)d_in[2];
    const int*   stridep = (const int*)d_in[3];
    float* out = (float*)d_out;
    char* ws = (char*)d_ws;

    uint32_t* mkey = (uint32_t*)(ws + OFF_MKEY);
    uint8_t*  cls  = (uint8_t*)(ws + OFF_CLS);
    uint32_t* hist = (uint32_t*)(ws + OFF_HIST);
    uint32_t* scal = (uint32_t*)(ws + OFF_SCAL);
    unsigned long long* grp = (unsigned long long*)(ws + OFF_GRP);
    unsigned long long* cand = (unsigned long long*)(ws + OFF_CAND);
    uint64_t* mask = (uint64_t*)(ws + OFF_MASK);

    k_scoremax<<<dim3(1024), dim3(256), 0, stream>>>(logits, mkey, cls, hist);
    k_select<<<dim3(256), dim3(256), 0, stream>>>(mkey, hist, scal, cand,
                                                  deltas, locs, stridep, cls, out);
    k_maskscan<<<dim3(500), dim3(256), 0, stream>>>(out, scal, mask, grp, out);
}